// Round 1
// 164.959 us; speedup vs baseline: 1.0691x; 1.0691x over previous
//
#include <hip/hip_runtime.h>

#define GAMMA 0.1f
#define MIN_R 0.1f

// Counting-sort-by-range parameters
#define NR 1024                 // nodes per range (power of 2)
#define LOG_NR 10
#define S3 (3 * NR)             // floats per x-slice / accumulator (12 KB)
#define NB 256                  // blocks for count/scatter kernels
#define THR_AC 256              // threads for count/scatter
#define THR_D 256               // threads for process kernel
#define RMAX 128                // max ranges supported (n_nodes <= 131072)
#define BPR 12                  // blocks per range in process phase

// ---------------- phase A: per-block range histogram -------------------------
__global__ __launch_bounds__(THR_AC) void count_kernel(
    const int* __restrict__ dst, unsigned* __restrict__ counts,
    int n_edges, int epb, int R)
{
    __shared__ unsigned hist[RMAX];
    const int b = blockIdx.x, t = threadIdx.x;
    if (t < RMAX) hist[t] = 0;
    __syncthreads();
    const int s0 = b * epb;
    const int s1 = min(s0 + epb, n_edges);
    for (int base = s0 + t * 4; base < s1; base += THR_AC * 4) {
        if (base + 3 < s1) {
            int4 d4 = *(const int4*)(dst + base);
            atomicAdd(&hist[(unsigned)d4.x >> LOG_NR], 1u);
            atomicAdd(&hist[(unsigned)d4.y >> LOG_NR], 1u);
            atomicAdd(&hist[(unsigned)d4.z >> LOG_NR], 1u);
            atomicAdd(&hist[(unsigned)d4.w >> LOG_NR], 1u);
        } else {
            for (int e = base; e < s1; ++e)
                atomicAdd(&hist[(unsigned)dst[e] >> LOG_NR], 1u);
        }
    }
    __syncthreads();
    if (t < R) counts[b * R + t] = hist[t];
}

// ---------------- phase B1: per-bin exclusive scan over blocks ---------------
__global__ __launch_bounds__(NB) void scan_blocks_kernel(
    const unsigned* __restrict__ counts, unsigned* __restrict__ bases,
    unsigned* __restrict__ totals, int R)
{
    __shared__ unsigned s[NB];
    const int r = blockIdx.x, t = threadIdx.x;
    unsigned orig = counts[t * R + r];
    s[t] = orig;
    __syncthreads();
    for (int d = 1; d < NB; d <<= 1) {
        unsigned v = (t >= d) ? s[t - d] : 0u;
        __syncthreads();
        s[t] += v;
        __syncthreads();
    }
    bases[t * R + r] = s[t] - orig;           // exclusive
    if (t == NB - 1) totals[r] = s[t];
}

// ---------------- phase B2: exclusive scan over bins -------------------------
__global__ void scan_bins_kernel(const unsigned* __restrict__ totals,
                                 unsigned* __restrict__ offsets, int R)
{
    __shared__ unsigned tot[RMAX];
    const int t = threadIdx.x;
    if (t < R) tot[t] = totals[t];
    __syncthreads();
    if (t == 0) {
        unsigned off = 0;
        for (int r = 0; r < R; ++r) { offsets[r] = off; off += tot[r]; }
        offsets[R] = off;
    }
}

// ---------------- phase C: scatter packed edges into bins --------------------
__global__ __launch_bounds__(THR_AC) void scatter_kernel(
    const int* __restrict__ src, const int* __restrict__ dst,
    const unsigned* __restrict__ bases, const unsigned* __restrict__ offsets,
    unsigned* __restrict__ pk, int n_edges, int epb, int R)
{
    __shared__ unsigned cursor[RMAX];
    const int b = blockIdx.x, t = threadIdx.x;
    if (t < R) cursor[t] = bases[b * R + t] + offsets[t];
    __syncthreads();
    const int s0 = b * epb;
    const int s1 = min(s0 + epb, n_edges);
    for (int base = s0 + t * 4; base < s1; base += THR_AC * 4) {
        if (base + 3 < s1) {
            int4 d4 = *(const int4*)(dst + base);
            int4 s4 = *(const int4*)(src + base);
            #pragma unroll
            for (int k = 0; k < 4; ++k) {
                unsigned d = (unsigned)((k == 0) ? d4.x : (k == 1) ? d4.y : (k == 2) ? d4.z : d4.w);
                unsigned s = (unsigned)((k == 0) ? s4.x : (k == 1) ? s4.y : (k == 2) ? s4.z : s4.w);
                unsigned r = d >> LOG_NR;
                unsigned u = d & (NR - 1);
                unsigned pos = atomicAdd(&cursor[r], 1u);
                pk[pos] = (u << 17) | s;
            }
        } else {
            for (int e = base; e < s1; ++e) {
                unsigned d = (unsigned)dst[e];
                unsigned r = d >> LOG_NR;
                unsigned u = d & (NR - 1);
                unsigned pos = atomicAdd(&cursor[r], 1u);
                pk[pos] = (u << 17) | (unsigned)src[e];
            }
        }
    }
}

// ---------------- phase D: dense per-range LJ accumulate ---------------------
// grid = (BPR, R). Block (b, r): process slice of bin r, accumulate in LDS,
// then atomically merge its 12 KB accumulator into out (pre-init'd to -gamma*v).
__device__ __forceinline__ void lj_force3(float dx, float dy, float dz,
                                          float& fx, float& fy, float& fz)
{
    float r2 = dx * dx + dy * dy + dz * dz;
    float rr = sqrtf(r2);
    float inv_norm = 1.0f / fmaxf(rr, 1e-12f);
    float rc = fmaxf(rr, MIN_R);
    float s1 = 1.0f / rc;                 // RC = 1
    float s2 = s1 * s1;
    float s6 = s2 * s2 * s2;
    float F = 4.0f * s6 * (12.0f * s6 - 6.0f) * s1;
    float sc = F * inv_norm;
    fx = sc * dx; fy = sc * dy; fz = sc * dz;
}

__global__ __launch_bounds__(THR_D) void process_kernel(
    const float* __restrict__ x, const unsigned* __restrict__ pk,
    const unsigned* __restrict__ offsets, float* __restrict__ out,
    int n_nodes, int bpr)
{
    __shared__ __align__(16) float acc[S3];
    __shared__ __align__(16) float xr[S3];
    const int b = blockIdx.x, r = blockIdx.y, t = threadIdx.x;
    const int xbase = 3 * (r << LOG_NR);
    const int xlim = 3 * n_nodes;
    for (int i = t; i < S3; i += THR_D) {
        acc[i] = 0.0f;
        int g = xbase + i;
        xr[i] = (g < xlim) ? x[g] : 0.0f;
    }
    __syncthreads();

    const int e0 = (int)offsets[r];
    const int e1 = (int)offsets[r + 1];
    const int cnt = e1 - e0;
    const int ebp = (((cnt + bpr - 1) / bpr) + 3) & ~3;   // multiple of 4
    const int st = e0 + b * ebp;
    const int en = min(st + ebp, e1);

    // 4-edge unrolled main loop: 4 independent gathers in flight per thread.
    int i = st + 4 * t;
    for (; i + 3 < en; i += 4 * THR_D) {
        unsigned p[4];
        int sI[4], uI[4];
        float xs[4][3];
        #pragma unroll
        for (int k = 0; k < 4; ++k)
            p[k] = __builtin_nontemporal_load(pk + i + k);
        #pragma unroll
        for (int k = 0; k < 4; ++k) {
            sI[k] = 3 * (int)(p[k] & 0x1FFFFu);
            uI[k] = 3 * (int)(p[k] >> 17);
        }
        #pragma unroll
        for (int k = 0; k < 4; ++k) {
            xs[k][0] = x[sI[k] + 0];
            xs[k][1] = x[sI[k] + 1];
            xs[k][2] = x[sI[k] + 2];
        }
        #pragma unroll
        for (int k = 0; k < 4; ++k) {
            float dx = xr[uI[k] + 0] - xs[k][0];
            float dy = xr[uI[k] + 1] - xs[k][1];
            float dz = xr[uI[k] + 2] - xs[k][2];
            float fx, fy, fz;
            lj_force3(dx, dy, dz, fx, fy, fz);
            unsafeAtomicAdd(&acc[uI[k] + 0], fx);
            unsafeAtomicAdd(&acc[uI[k] + 1], fy);
            unsafeAtomicAdd(&acc[uI[k] + 2], fz);
        }
    }
    // tail: at most 3 edges per thread, only in the last block of a range
    if (i < en) {
        for (int e = i; e < en; ++e) {
            unsigned p = pk[e];
            int s = 3 * (int)(p & 0x1FFFFu);
            int u = 3 * (int)(p >> 17);
            float dx = xr[u + 0] - x[s + 0];
            float dy = xr[u + 1] - x[s + 1];
            float dz = xr[u + 2] - x[s + 2];
            float fx, fy, fz;
            lj_force3(dx, dy, dz, fx, fy, fz);
            unsafeAtomicAdd(&acc[u + 0], fx);
            unsafeAtomicAdd(&acc[u + 1], fy);
            unsafeAtomicAdd(&acc[u + 2], fz);
        }
    }
    __syncthreads();

    // epilogue: coalesced atomic merge into out (already holds -gamma*v)
    for (int j = t; j < S3; j += THR_D) {
        int g = xbase + j;
        if (g < xlim) unsafeAtomicAdd(&out[g], acc[j]);
    }
}

// ---------------- out init (+ fallback path) ---------------------------------
__global__ void init_out_kernel(const float* __restrict__ v,
                                float* __restrict__ out, int n) {
    int i = blockIdx.x * blockDim.x + threadIdx.x;
    if (i < n) out[i] = -GAMMA * v[i];
}

__global__ void edge_atomic_kernel(const float* __restrict__ x,
                                   const int* __restrict__ src,
                                   const int* __restrict__ dst,
                                   float* __restrict__ out, int n_edges) {
    int t = blockIdx.x * blockDim.x + threadIdx.x;
    int e = t;
    if (e < n_edges) {
        int s = src[e], d = dst[e];
        float dx = x[3 * d + 0] - x[3 * s + 0];
        float dy = x[3 * d + 1] - x[3 * s + 1];
        float dz = x[3 * d + 2] - x[3 * s + 2];
        float fx, fy, fz;
        lj_force3(dx, dy, dz, fx, fy, fz);
        unsafeAtomicAdd(&out[3 * d + 0], fx);
        unsafeAtomicAdd(&out[3 * d + 1], fy);
        unsafeAtomicAdd(&out[3 * d + 2], fz);
    }
}

extern "C" void kernel_launch(void* const* d_in, const int* in_sizes, int n_in,
                              void* d_out, int out_size, void* d_ws, size_t ws_size,
                              hipStream_t stream) {
    const float* x   = (const float*)d_in[0];
    const float* v   = (const float*)d_in[1];
    const int*   src = (const int*)d_in[2];
    const int*   dst = (const int*)d_in[3];
    float* out = (float*)d_out;

    const int n_out = out_size;
    const int n_nodes = out_size / 3;
    const int n_edges = in_sizes[2];
    const int R = (n_nodes + NR - 1) / NR;

    // ws layout (u32 units for tables)
    const size_t counts_off  = 0;                       // NB*R
    const size_t bases_off   = (size_t)NB * R;          // NB*R
    const size_t totals_off  = 2 * (size_t)NB * R;      // R
    const size_t offsets_off = totals_off + R;          // R+1
    const size_t tables_end  = offsets_off + R + 1;
    const size_t pk_byte_off = ((tables_end * 4) + 63) & ~(size_t)63;
    const size_t need = pk_byte_off + (size_t)n_edges * 4;

    const int blk = 256;
    const bool fast = (n_nodes <= (1 << 17)) && (R <= RMAX) && (need <= ws_size);

    if (fast) {
        unsigned* tables  = (unsigned*)d_ws;
        unsigned* counts  = tables + counts_off;
        unsigned* bases   = tables + bases_off;
        unsigned* totals  = tables + totals_off;
        unsigned* offsets = tables + offsets_off;
        unsigned* pk      = (unsigned*)((char*)d_ws + pk_byte_off);

        int epb = ((n_edges + NB - 1) / NB + 3) & ~3;

        init_out_kernel<<<(n_out + blk - 1) / blk, blk, 0, stream>>>(v, out, n_out);
        count_kernel<<<NB, THR_AC, 0, stream>>>(dst, counts, n_edges, epb, R);
        scan_blocks_kernel<<<R, NB, 0, stream>>>(counts, bases, totals, R);
        scan_bins_kernel<<<1, RMAX, 0, stream>>>(totals, offsets, R);
        scatter_kernel<<<NB, THR_AC, 0, stream>>>(src, dst, bases, offsets, pk,
                                                  n_edges, epb, R);
        dim3 gridD(BPR, R);
        process_kernel<<<gridD, THR_D, 0, stream>>>(x, pk, offsets, out,
                                                    n_nodes, BPR);
    } else {
        init_out_kernel<<<(n_out + blk - 1) / blk, blk, 0, stream>>>(v, out, n_out);
        edge_atomic_kernel<<<(n_edges + blk - 1) / blk, blk, 0, stream>>>(
            x, src, dst, out, n_edges);
    }
}